// Round 8
// baseline (382.781 us; speedup 1.0000x reference)
//
#include <hip/hip_runtime.h>

#define LLEN 8192
#define CG 16
#define NG 512   // b(16) * GROUPS(32)

typedef float f32x4 __attribute__((ext_vector_type(4)));

__device__ __forceinline__ uint32_t bf16rne(float f) {
    uint32_t u = __float_as_uint(f);
    return (u + 0x7FFFu + ((u >> 16) & 1u)) >> 16;
}
__device__ __forceinline__ uint32_t packbf(float lo, float hi) {
    return bf16rne(lo) | (bf16rne(hi) << 16);
}
__device__ __forceinline__ float unlo(uint32_t p) { return __uint_as_float(p << 16); }
__device__ __forceinline__ float unhi(uint32_t p) { return __uint_as_float(p & 0xFFFF0000u); }

#define XB_U32 2048                        // u32 per LDS row (4096 bf16 cols)
#define LDS_XB_BYTES (CG * XB_U32 * 4)     // 131072
#define LDS_TOTAL (LDS_XB_BYTES + (256 + 256 + 256 + 16 + 16 + 49) * 4)

// One block per group; 1024 threads = 16 waves; 1 block/CU (128 KiB LDS).
// Cols [0,4096) live in registers as packed bf16 (32 u32/lane);
// cols [4096,8192) live in LDS as packed bf16. Zero HBM re-read of x.
// amdgpu_waves_per_eu(4,4): pin allocator target to 4 waves/EU -> 128-VGPR cap
// (default heuristic saw ~0 static LDS, targeted 8 waves/EU, capped at 64 and
// spilled ~700 MB of scratch per launch in rounds 6-7).
extern "C" __global__ __launch_bounds__(1024)
__attribute__((amdgpu_waves_per_eu(4, 4))) void fused_kernel(
        const float* __restrict__ x,  const float* __restrict__ w1,
        const float* __restrict__ b1, const float* __restrict__ w3,
        const float* __restrict__ b3, float* __restrict__ out) {
    extern __shared__ char smem[];
    uint32_t* XB    = (uint32_t*)smem;                  // [CG][2048] packed bf16
    float*    Spart = (float*)(smem + LDS_XB_BYTES);    // [16][16] wave-partial row sums
    float*    eL    = Spart + 256;                      // [16][16] x[i][256w]
    float*    eR    = eL + 256;                         // [16][16] x[i][256w+255]
    float*    F_l   = eR + 256;                         // [16] x[i][0]
    float*    L_l   = F_l + CG;                         // [16] x[i][8191]
    float*    V     = L_l + CG;                         // [49] v0,v1,v2,cb

    const int g    = blockIdx.x;
    const int wave = threadIdx.x >> 6;
    const int lane = threadIdx.x & 63;
    const size_t rowbase = (size_t)g * CG * LLEN;
    const int cA   = 256 * wave + 4 * lane;             // reg-half col
    const int cB   = 4096 + cA;                         // LDS-half col
    const int bidx = 128 * wave + 2 * lane;             // u32 index into XB row

    // ---------------- phase 1: load, row-sum, pack (regs + LDS) ----------------
    uint2 xA[CG];
    #pragma unroll
    for (int i = 0; i < CG; ++i) {
        const float* rp = x + rowbase + (size_t)i * LLEN;
        float4 a = *reinterpret_cast<const float4*>(rp + cA);
        float4 b = *reinterpret_cast<const float4*>(rp + cB);
        float s = ((a.x + a.y) + (a.z + a.w)) + ((b.x + b.y) + (b.z + b.w));
        #pragma unroll
        for (int off = 32; off; off >>= 1) s += __shfl_xor(s, off, 64);
        if (lane == 0) Spart[wave * CG + i] = s;        // static index only
        xA[i].x = packbf(a.x, a.y);
        xA[i].y = packbf(a.z, a.w);
        *reinterpret_cast<uint2*>(&XB[i * XB_U32 + bidx]) =
            make_uint2(packbf(b.x, b.y), packbf(b.z, b.w));
        if (lane == 0)  eL[wave * CG + i] = a.x;
        if (lane == 63) eR[wave * CG + i] = a.w;
        if (wave == 0  && lane == 0)  F_l[i] = a.x;
        if (wave == 15 && lane == 63) L_l[i] = b.w;
    }
    __syncthreads();

    // ---------------- prep: softmax -> collapsed taps (wave 0) ----------------
    if (wave == 0) {
        const int i = lane & 15;
        float S = 0.f;
        #pragma unroll
        for (int w = 0; w < CG; ++w) S += Spart[w * CG + i];
        float Fv = F_l[i], Lv = L_l[i];
        const float invL = 1.0f / (float)LLEN;
        float s1 = 0.f, s2 = 0.f;
        #pragma unroll
        for (int k = 0; k < CG; ++k) {
            float Sk = __shfl(S,  k, 16);
            float Fk = __shfl(Fv, k, 16);
            float Lk = __shfl(Lv, k, 16);
            s1 += w1[i * CG + k] * Sk;
            const float* w = &w3[(i * CG + k) * 3];
            s2 += w[0] * (Sk - Lk) + w[1] * Sk + w[2] * (Sk - Fk);
        }
        float m1 = s1 * invL + b1[i];
        float m2 = s2 * invL + b3[i];

        float mx1 = m1, mx2 = m2;
        #pragma unroll
        for (int off = 8; off; off >>= 1) {
            mx1 = fmaxf(mx1, __shfl_xor(mx1, off, 16));
            mx2 = fmaxf(mx2, __shfl_xor(mx2, off, 16));
        }
        float e1 = __expf(m1 - mx1), e2 = __expf(m2 - mx2);
        float d1 = e1, d2 = e2;
        #pragma unroll
        for (int off = 8; off; off >>= 1) {
            d1 += __shfl_xor(d1, off, 16);
            d2 += __shfl_xor(d2, off, 16);
        }
        float a1 = e1 / d1, a2 = e2 / d2;

        float cb = a1 * b3[i] + a2 * b1[i];
        #pragma unroll
        for (int off = 8; off; off >>= 1) cb += __shfl_xor(cb, off, 16);

        float v0 = 0.f, v1v = 0.f, v2 = 0.f;
        #pragma unroll
        for (int k = 0; k < CG; ++k) {
            float a1k = __shfl(a1, k, 16);
            float a2k = __shfl(a2, k, 16);
            const float* w = &w3[(k * CG + i) * 3];
            v0  += a1k * w[0];
            v1v += a1k * w[1] + a2k * w1[k * CG + i];
            v2  += a1k * w[2];
        }
        if (lane < 16) {
            V[i]      = v0;
            V[16 + i] = v1v;
            V[32 + i] = v2;
            if (lane == 0) V[48] = cb;
        }
    }
    __syncthreads();

    // ---------------- phase 2: 3-tap gate (regs + LDS), accumulate over rows ----
    const float cbv = V[48];
    float wA0 = cbv, wA1 = cbv, wA2 = cbv, wA3 = cbv;
    float wB0 = cbv, wB1 = cbv, wB2 = cbv, wB3 = cbv;
    #pragma unroll
    for (int i = 0; i < CG; ++i) {
        float a0 = unlo(xA[i].x), a1 = unhi(xA[i].x);
        float a2 = unlo(xA[i].y), a3 = unhi(xA[i].y);
        uint2 bw = *reinterpret_cast<const uint2*>(&XB[i * XB_U32 + bidx]);
        float b0 = unlo(bw.x), b1v = unhi(bw.x);
        float b2 = unlo(bw.y), b3v = unhi(bw.y);

        float pA = __shfl_up(a3, 1, 64);
        float nA = __shfl_down(a0, 1, 64);
        float pB = __shfl_up(b3v, 1, 64);
        float nB = __shfl_down(b0, 1, 64);
        if (lane == 0)  pA = wave ? eR[(wave - 1) * CG + i] : 0.f;
        if (lane == 63) nA = (wave < 15) ? eL[(wave + 1) * CG + i]
                                         : unlo(XB[i * XB_U32]);
        if (lane == 0)  pB = wave ? unhi(XB[i * XB_U32 + 128 * wave - 1])
                                  : eR[15 * CG + i];
        if (lane == 63) nB = (wave < 15) ? unlo(XB[i * XB_U32 + 128 * wave + 128])
                                         : 0.f;

        const float v0 = V[i], v1c = V[16 + i], v2c = V[32 + i];
        wA0 += v0 * pA  + v1c * a0  + v2c * a1;
        wA1 += v0 * a0  + v1c * a1  + v2c * a2;
        wA2 += v0 * a1  + v1c * a2  + v2c * a3;
        wA3 += v0 * a2  + v1c * a3  + v2c * nA;
        wB0 += v0 * pB  + v1c * b0  + v2c * b1v;
        wB1 += v0 * b0  + v1c * b1v + v2c * b2;
        wB2 += v0 * b1v + v1c * b2  + v2c * b3v;
        wB3 += v0 * b2  + v1c * b3v + v2c * nB;
    }
    const float sA0 = 1.f / (1.f + __expf(-wA0));
    const float sA1 = 1.f / (1.f + __expf(-wA1));
    const float sA2 = 1.f / (1.f + __expf(-wA2));
    const float sA3 = 1.f / (1.f + __expf(-wA3));
    const float sB0 = 1.f / (1.f + __expf(-wB0));
    const float sB1 = 1.f / (1.f + __expf(-wB1));
    const float sB2 = 1.f / (1.f + __expf(-wB2));
    const float sB3 = 1.f / (1.f + __expf(-wB3));

    #pragma unroll
    for (int i = 0; i < CG; ++i) {
        float* rp = out + rowbase + (size_t)i * LLEN;
        uint2 bw = *reinterpret_cast<const uint2*>(&XB[i * XB_U32 + bidx]);
        f32x4 oa = { unlo(xA[i].x) * sA0, unhi(xA[i].x) * sA1,
                     unlo(xA[i].y) * sA2, unhi(xA[i].y) * sA3 };
        f32x4 ob = { unlo(bw.x) * sB0, unhi(bw.x) * sB1,
                     unlo(bw.y) * sB2, unhi(bw.y) * sB3 };
        *reinterpret_cast<f32x4*>(rp + cA) = oa;
        *reinterpret_cast<f32x4*>(rp + cB) = ob;
    }
}

extern "C" void kernel_launch(void* const* d_in, const int* in_sizes, int n_in,
                              void* d_out, int out_size, void* d_ws, size_t ws_size,
                              hipStream_t stream) {
    const float* x  = (const float*)d_in[0];
    const float* w1 = (const float*)d_in[1];
    const float* b1 = (const float*)d_in[2];
    const float* w3 = (const float*)d_in[3];
    const float* b3 = (const float*)d_in[4];
    float* out = (float*)d_out;

    // Allow >64 KiB dynamic LDS (host-side, not stream-ordered: graph-safe).
    (void)hipFuncSetAttribute((const void*)fused_kernel,
                              hipFuncAttributeMaxDynamicSharedMemorySize, LDS_TOTAL);
    fused_kernel<<<NG, 1024, LDS_TOTAL, stream>>>(x, w1, b1, w3, b3, out);
}

// Round 9
// 257.351 us; speedup vs baseline: 1.4874x; 1.4874x over previous
//
#include <hip/hip_runtime.h>

#define LLEN 8192
#define CG 16
#define NG 512   // b(16) * GROUPS(32)

typedef float f32x4 __attribute__((ext_vector_type(4)));

__device__ __forceinline__ uint32_t bf16rne(float f) {
    uint32_t u = __float_as_uint(f);
    return (u + 0x7FFFu + ((u >> 16) & 1u)) >> 16;
}
__device__ __forceinline__ uint32_t packbf(float lo, float hi) {
    return bf16rne(lo) | (bf16rne(hi) << 16);
}
__device__ __forceinline__ float unlo(uint32_t p) { return __uint_as_float(p << 16); }
__device__ __forceinline__ float unhi(uint32_t p) { return __uint_as_float(p & 0xFFFF0000u); }

// One block per group; 512 threads = 8 waves; STATIC 132 KiB LDS -> compiler's
// occupancy model derives 1 block/CU (2 waves/EU) -> VGPR cap 256 (vs the 64
// it granted the 1024-thr dynamic-LDS versions, which spilled ~700 MB/launch).
// Cols [0,4096): registers, packed bf16 (64 u32/lane = 4/row).
// Cols [4096,8192): LDS, packed bf16 (XB[row][k] = cols 4096+2k, 4096+2k+1).
// Zero HBM re-read of x. Demand ~105 VGPR -> fits even a 128 cap.
extern "C" __global__ __launch_bounds__(512)
__attribute__((amdgpu_waves_per_eu(2, 2))) void fused_kernel(
        const float* __restrict__ x,  const float* __restrict__ w1,
        const float* __restrict__ b1, const float* __restrict__ w3,
        const float* __restrict__ b3, float* __restrict__ out) {
    __shared__ uint32_t XB[CG][2048];      // 131072 B
    __shared__ float Spart[8][CG];         // per-wave row-sum partials
    __shared__ float eL[8][CG];            // x[row][512w]       (A-run first col)
    __shared__ float eR[8][CG];            // x[row][512w+511]   (B-run last col)
    __shared__ float V[49];                // v0[0:16) v1[16:32) v2[32:48) cb

    const int g   = blockIdx.x;
    const int tid = threadIdx.x;
    const int w   = tid >> 6;
    const int l   = tid & 63;
    const size_t rowbase = (size_t)g * CG * LLEN;
    const int cA = 512 * w + 4 * l;        // reg A-run col
    const int cB = cA + 256;               // reg B-run col
    const int cC = 4096 + 4 * tid;         // LDS C cols (block-dense)
    const int cD = 6144 + 4 * tid;         // LDS D cols
    const int k1 = 2 * tid;                // XB u32 idx for C group
    const int k2 = 1024 + 2 * tid;         // XB u32 idx for D group

    // ---------------- phase 1: load, row-sum, pack (regs + LDS) ----------------
    uint4 xr[CG];                          // .x/.y = A cols, .z/.w = B cols
    #pragma unroll
    for (int i = 0; i < CG; ++i) {
        const float* rp = x + rowbase + (size_t)i * LLEN;
        f32x4 a = *reinterpret_cast<const f32x4*>(rp + cA);
        f32x4 b = *reinterpret_cast<const f32x4*>(rp + cB);
        f32x4 c = *reinterpret_cast<const f32x4*>(rp + cC);
        f32x4 d = *reinterpret_cast<const f32x4*>(rp + cD);
        float s = ((a.x + a.y) + (a.z + a.w)) + ((b.x + b.y) + (b.z + b.w))
                + ((c.x + c.y) + (c.z + c.w)) + ((d.x + d.y) + (d.z + d.w));
        #pragma unroll
        for (int off = 32; off; off >>= 1) s += __shfl_xor(s, off, 64);
        if (l == 0)  { Spart[w][i] = s; eL[w][i] = a.x; }
        if (l == 63) eR[w][i] = b.w;
        xr[i].x = packbf(a.x, a.y);  xr[i].y = packbf(a.z, a.w);
        xr[i].z = packbf(b.x, b.y);  xr[i].w = packbf(b.z, b.w);
        *reinterpret_cast<uint2*>(&XB[i][k1]) = make_uint2(packbf(c.x, c.y), packbf(c.z, c.w));
        *reinterpret_cast<uint2*>(&XB[i][k2]) = make_uint2(packbf(d.x, d.y), packbf(d.z, d.w));
    }
    __syncthreads();

    // ---------------- prep: softmax -> collapsed taps (wave 0) ----------------
    if (w == 0) {
        const int i = l & 15;
        float S = 0.f;
        #pragma unroll
        for (int p = 0; p < 8; ++p) S += Spart[p][i];
        float Fv = eL[0][i];
        float Lv = unhi(XB[i][2047]);      // col 8191
        const float invL = 1.0f / (float)LLEN;
        float s1 = 0.f, s2 = 0.f;
        #pragma unroll
        for (int k = 0; k < CG; ++k) {
            float Sk = __shfl(S,  k, 16);
            float Fk = __shfl(Fv, k, 16);
            float Lk = __shfl(Lv, k, 16);
            s1 += w1[i * CG + k] * Sk;
            const float* wp = &w3[(i * CG + k) * 3];
            s2 += wp[0] * (Sk - Lk) + wp[1] * Sk + wp[2] * (Sk - Fk);
        }
        float m1 = s1 * invL + b1[i];
        float m2 = s2 * invL + b3[i];

        float mx1 = m1, mx2 = m2;
        #pragma unroll
        for (int off = 8; off; off >>= 1) {
            mx1 = fmaxf(mx1, __shfl_xor(mx1, off, 16));
            mx2 = fmaxf(mx2, __shfl_xor(mx2, off, 16));
        }
        float e1 = __expf(m1 - mx1), e2 = __expf(m2 - mx2);
        float d1 = e1, d2 = e2;
        #pragma unroll
        for (int off = 8; off; off >>= 1) {
            d1 += __shfl_xor(d1, off, 16);
            d2 += __shfl_xor(d2, off, 16);
        }
        float a1 = e1 / d1, a2 = e2 / d2;

        float cb = a1 * b3[i] + a2 * b1[i];
        #pragma unroll
        for (int off = 8; off; off >>= 1) cb += __shfl_xor(cb, off, 16);

        float v0 = 0.f, v1v = 0.f, v2 = 0.f;
        #pragma unroll
        for (int k = 0; k < CG; ++k) {
            float a1k = __shfl(a1, k, 16);
            float a2k = __shfl(a2, k, 16);
            const float* wp = &w3[(k * CG + i) * 3];
            v0  += a1k * wp[0];
            v1v += a1k * wp[1] + a2k * w1[k * CG + i];
            v2  += a1k * wp[2];
        }
        if (l < 16) {
            V[i]      = v0;
            V[16 + i] = v1v;
            V[32 + i] = v2;
            if (l == 0) V[48] = cb;
        }
    }
    __syncthreads();

    // ---------------- phase 2: 3-tap weight accumulation over rows ----------------
    const float cbv = V[48];
    float wA0 = cbv, wA1 = cbv, wA2 = cbv, wA3 = cbv;
    float wB0 = cbv, wB1 = cbv, wB2 = cbv, wB3 = cbv;
    float wC0 = cbv, wC1 = cbv, wC2 = cbv, wC3 = cbv;
    float wD0 = cbv, wD1 = cbv, wD2 = cbv, wD3 = cbv;
    #pragma unroll
    for (int i = 0; i < CG; ++i) {
        float a0 = unlo(xr[i].x), a1 = unhi(xr[i].x);
        float a2 = unlo(xr[i].y), a3 = unhi(xr[i].y);
        float b0 = unlo(xr[i].z), b1v = unhi(xr[i].z);
        float b2 = unlo(xr[i].w), b3v = unhi(xr[i].w);

        float pA = __shfl_up(a3, 1, 64);
        float nA = __shfl_down(a0, 1, 64);
        float pB = __shfl_up(b3v, 1, 64);
        float nB = __shfl_down(b0, 1, 64);
        float b0l0  = __shfl(b0, 0, 64);
        float a3l63 = __shfl(a3, 63, 64);
        if (l == 0)  pA = w ? eR[w - 1][i] : 0.f;
        if (l == 63) nA = b0l0;
        if (l == 0)  pB = a3l63;
        if (l == 63) nB = (w < 7) ? eL[w + 1][i] : unlo(XB[i][0]);

        uint2 mC = *reinterpret_cast<const uint2*>(&XB[i][k1]);
        uint2 mD = *reinterpret_cast<const uint2*>(&XB[i][k2]);
        float c0 = unlo(mC.x), c1 = unhi(mC.x), c2 = unlo(mC.y), c3 = unhi(mC.y);
        float d0 = unlo(mD.x), d1v = unhi(mD.x), d2 = unlo(mD.y), d3v = unhi(mD.y);
        float pC = k1 ? unhi(XB[i][k1 - 1]) : eR[7][i];       // col 4095
        float nC = unlo(XB[i][k1 + 2]);                        // contiguous into D
        float pD = unhi(XB[i][k2 - 1]);
        float nD = (k2 + 2 < 2048) ? unlo(XB[i][k2 + 2]) : 0.f;  // col 8192 -> 0

        const float v0 = V[i], v1c = V[16 + i], v2c = V[32 + i];
        wA0 += v0 * pA  + v1c * a0  + v2c * a1;
        wA1 += v0 * a0  + v1c * a1  + v2c * a2;
        wA2 += v0 * a1  + v1c * a2  + v2c * a3;
        wA3 += v0 * a2  + v1c * a3  + v2c * nA;
        wB0 += v0 * pB  + v1c * b0  + v2c * b1v;
        wB1 += v0 * b0  + v1c * b1v + v2c * b2;
        wB2 += v0 * b1v + v1c * b2  + v2c * b3v;
        wB3 += v0 * b2  + v1c * b3v + v2c * nB;
        wC0 += v0 * pC  + v1c * c0  + v2c * c1;
        wC1 += v0 * c0  + v1c * c1  + v2c * c2;
        wC2 += v0 * c1  + v1c * c2  + v2c * c3;
        wC3 += v0 * c2  + v1c * c3  + v2c * nC;
        wD0 += v0 * pD  + v1c * d0  + v2c * d1v;
        wD1 += v0 * d0  + v1c * d1v + v2c * d2;
        wD2 += v0 * d1v + v1c * d2  + v2c * d3v;
        wD3 += v0 * d2  + v1c * d3v + v2c * nD;
    }
    const float sA0 = 1.f / (1.f + __expf(-wA0));
    const float sA1 = 1.f / (1.f + __expf(-wA1));
    const float sA2 = 1.f / (1.f + __expf(-wA2));
    const float sA3 = 1.f / (1.f + __expf(-wA3));
    const float sB0 = 1.f / (1.f + __expf(-wB0));
    const float sB1 = 1.f / (1.f + __expf(-wB1));
    const float sB2 = 1.f / (1.f + __expf(-wB2));
    const float sB3 = 1.f / (1.f + __expf(-wB3));
    const float sC0 = 1.f / (1.f + __expf(-wC0));
    const float sC1 = 1.f / (1.f + __expf(-wC1));
    const float sC2 = 1.f / (1.f + __expf(-wC2));
    const float sC3 = 1.f / (1.f + __expf(-wC3));
    const float sD0 = 1.f / (1.f + __expf(-wD0));
    const float sD1 = 1.f / (1.f + __expf(-wD1));
    const float sD2 = 1.f / (1.f + __expf(-wD2));
    const float sD3 = 1.f / (1.f + __expf(-wD3));

    // ---------------- store ----------------
    #pragma unroll
    for (int i = 0; i < CG; ++i) {
        float* rp = out + rowbase + (size_t)i * LLEN;
        uint2 mC = *reinterpret_cast<const uint2*>(&XB[i][k1]);
        uint2 mD = *reinterpret_cast<const uint2*>(&XB[i][k2]);
        f32x4 oa = { unlo(xr[i].x) * sA0, unhi(xr[i].x) * sA1,
                     unlo(xr[i].y) * sA2, unhi(xr[i].y) * sA3 };
        f32x4 ob = { unlo(xr[i].z) * sB0, unhi(xr[i].z) * sB1,
                     unlo(xr[i].w) * sB2, unhi(xr[i].w) * sB3 };
        f32x4 oc = { unlo(mC.x) * sC0, unhi(mC.x) * sC1,
                     unlo(mC.y) * sC2, unhi(mC.y) * sC3 };
        f32x4 od = { unlo(mD.x) * sD0, unhi(mD.x) * sD1,
                     unlo(mD.y) * sD2, unhi(mD.y) * sD3 };
        *reinterpret_cast<f32x4*>(rp + cA) = oa;
        *reinterpret_cast<f32x4*>(rp + cB) = ob;
        *reinterpret_cast<f32x4*>(rp + cC) = oc;
        *reinterpret_cast<f32x4*>(rp + cD) = od;
    }
}

extern "C" void kernel_launch(void* const* d_in, const int* in_sizes, int n_in,
                              void* d_out, int out_size, void* d_ws, size_t ws_size,
                              hipStream_t stream) {
    const float* x  = (const float*)d_in[0];
    const float* w1 = (const float*)d_in[1];
    const float* b1 = (const float*)d_in[2];
    const float* w3 = (const float*)d_in[3];
    const float* b3 = (const float*)d_in[4];
    float* out = (float*)d_out;

    fused_kernel<<<NG, 512, 0, stream>>>(x, w1, b1, w3, b3, out);
}

// Round 10
// 164.710 us; speedup vs baseline: 2.3240x; 1.5625x over previous
//
#include <hip/hip_runtime.h>

#define LLEN 8192
#define CG 16
#define NG 512   // b(16) * GROUPS(32)

typedef float f32x4 __attribute__((ext_vector_type(4)));

// ---------------- Pass 1: row sums + per-group prep, fused. One block per group. ----
// 1024 threads = 16 waves; wave w sums row w. Then wave 0 computes softmax weights
// and the collapsed 3-tap vectors v0,v1,v2 and scalar bias c, writes vw[g*64..].
// Traverses groups in FORWARD dispatch order (g = blockIdx.x).
__global__ __launch_bounds__(1024) void sumprep_kernel(const float* __restrict__ x,
                                                       const float* __restrict__ w1,
                                                       const float* __restrict__ b1,
                                                       const float* __restrict__ w3,
                                                       const float* __restrict__ b3,
                                                       float* __restrict__ vw) {
    int g    = blockIdx.x;              // 0..511
    int wave = threadIdx.x >> 6;        // 0..15  == row within group
    int lane = threadIdx.x & 63;
    __shared__ float S_lds[CG], F_lds[CG], L_lds[CG];

    const float4* xr = reinterpret_cast<const float4*>(x + (size_t)(g * CG + wave) * LLEN);
    float s = 0.f;
    #pragma unroll
    for (int k = 0; k < 32; ++k) {
        float4 v = xr[k * 64 + lane];
        s += (v.x + v.y) + (v.z + v.w);
    }
    #pragma unroll
    for (int off = 32; off; off >>= 1)
        s += __shfl_down(s, off, 64);
    if (lane == 0) S_lds[wave] = s;
    if (threadIdx.x < CG) {
        size_t rb = (size_t)(g * CG + threadIdx.x) * LLEN;
        F_lds[threadIdx.x] = x[rb];
        L_lds[threadIdx.x] = x[rb + (LLEN - 1)];
    }
    __syncthreads();

    if (wave == 0) {
        int i = lane & 15;              // channel index (lanes 16..63 duplicate)
        const float invL = 1.0f / (float)LLEN;
        float s1 = 0.f, s2 = 0.f;
        #pragma unroll
        for (int k = 0; k < CG; ++k) {
            float Sk = S_lds[k], Fk = F_lds[k], Lk = L_lds[k];
            s1 += w1[i * CG + k] * Sk;
            const float* w = &w3[(i * CG + k) * 3];
            s2 += w[0] * (Sk - Lk) + w[1] * Sk + w[2] * (Sk - Fk);
        }
        float m1 = s1 * invL + b1[i];
        float m2 = s2 * invL + b3[i];

        // softmax across the 16-lane group (both heads)
        float mx1 = m1, mx2 = m2;
        #pragma unroll
        for (int off = 8; off; off >>= 1) {
            mx1 = fmaxf(mx1, __shfl_xor(mx1, off, 16));
            mx2 = fmaxf(mx2, __shfl_xor(mx2, off, 16));
        }
        float e1 = __expf(m1 - mx1), e2 = __expf(m2 - mx2);
        float d1 = e1, d2 = e2;
        #pragma unroll
        for (int off = 8; off; off >>= 1) {
            d1 += __shfl_xor(d1, off, 16);
            d2 += __shfl_xor(d2, off, 16);
        }
        float a1 = e1 / d1, a2 = e2 / d2;

        float cb = a1 * b3[i] + a2 * b1[i];
        #pragma unroll
        for (int off = 8; off; off >>= 1) cb += __shfl_xor(cb, off, 16);

        float v0 = 0.f, v1v = 0.f, v2 = 0.f;
        #pragma unroll
        for (int k = 0; k < CG; ++k) {
            float a1k = __shfl(a1, k, 16);
            float a2k = __shfl(a2, k, 16);
            const float* w = &w3[(k * CG + i) * 3];
            v0  += a1k * w[0];
            v1v += a1k * w[1] + a2k * w1[k * CG + i];
            v2  += a1k * w[2];
        }
        if (lane < 16) {
            float* outv = &vw[g * 64];
            outv[i]      = v0;
            outv[16 + i] = v1v;
            outv[32 + i] = v2;
            if (lane == 0) outv[48] = cb;
        }
    }
}

// ---------------- Pass 2: weights -> sigmoid gate -> output ----------------
// One wave per (group, 256-column chunk). REVERSE traversal: wave W handles
// group 511 - W/32, chunk 31 - W%32, so the first-touched x lines are the
// MRU lines sumprep left in L3; out-write evictions consume the LRU (low-g)
// lines instead of marching just ahead of the read front.
__global__ __launch_bounds__(256) void apply_kernel(const float* __restrict__ x,
                                                    const float* __restrict__ vw,
                                                    float* __restrict__ out) {
    int wavg = (blockIdx.x * 256 + threadIdx.x) >> 6;   // 0..16383
    int lane = threadIdx.x & 63;
    int g  = NG - 1 - (wavg >> 5);          // 511..0
    int c0 = (31 - (wavg & 31)) * 256;      // reverse chunks within group too
    const float* vp = &vw[g * 64];

    const float cb = vp[48];
    float w0 = cb, w1a = cb, w2a = cb, w3a = cb;
    float4 xv[CG];
    #pragma unroll
    for (int i = 0; i < CG; ++i) {
        size_t rb = ((size_t)(g * CG + i)) * LLEN + c0;
        float4 v = *reinterpret_cast<const float4*>(x + rb + 4 * lane);
        xv[i] = v;
        float le = 0.f, re = 0.f;
        if (c0 > 0)            le = x[rb - 1];          // uniform addr -> scalar load
        if (c0 + 256 < LLEN)   re = x[rb + 256];
        float fl = __shfl_up(v.w, 1, 64);
        if (lane == 0)  fl = le;
        float fr = __shfl_down(v.x, 1, 64);
        if (lane == 63) fr = re;
        const float a0 = vp[i], a1 = vp[16 + i], a2 = vp[32 + i];
        w0  += a0 * fl  + a1 * v.x + a2 * v.y;
        w1a += a0 * v.x + a1 * v.y + a2 * v.z;
        w2a += a0 * v.y + a1 * v.z + a2 * v.w;
        w3a += a0 * v.z + a1 * v.w + a2 * fr;
    }
    const float s0 = 1.f / (1.f + __expf(-w0));
    const float s1 = 1.f / (1.f + __expf(-w1a));
    const float s2 = 1.f / (1.f + __expf(-w2a));
    const float s3 = 1.f / (1.f + __expf(-w3a));
    #pragma unroll
    for (int i = 0; i < CG; ++i) {
        size_t rb = ((size_t)(g * CG + i)) * LLEN + c0 + 4 * lane;
        float4 v = xv[i];
        float4 o4 = make_float4(v.x * s0, v.y * s1, v.z * s2, v.w * s3);
        *reinterpret_cast<float4*>(out + rb) = o4;
    }
}

extern "C" void kernel_launch(void* const* d_in, const int* in_sizes, int n_in,
                              void* d_out, int out_size, void* d_ws, size_t ws_size,
                              hipStream_t stream) {
    const float* x  = (const float*)d_in[0];
    const float* w1 = (const float*)d_in[1];
    const float* b1 = (const float*)d_in[2];
    const float* w3 = (const float*)d_in[3];
    const float* b3 = (const float*)d_in[4];
    float* out = (float*)d_out;
    float* vw  = (float*)d_ws;              // 512 * 64 floats

    // Pass 1: one block per group, 16 waves (one per row), prep fused in-block.
    sumprep_kernel<<<NG, 1024, 0, stream>>>(x, w1, b1, w3, b3, vw);
    // Pass 2: 512 groups * 32 chunks = 16384 waves / 4 per block, reverse order.
    apply_kernel<<<4096, 256, 0, stream>>>(x, vw, out);
}